// Round 1
// baseline (674.835 us; speedup 1.0000x reference)
//
#include <hip/hip_runtime.h>

constexpr int N_IN  = 128;
constexpr int N_OUT = 32;

// ---------------- Kernel 1: h = feat @ W ----------------
// feat [n,128] f32, W [128,32] f32 (staged in LDS), h [n,32] f32.
// 8 threads per row; each thread computes 4 output columns (one float4).
__global__ __launch_bounds__(256) void gemm_h(
    const float* __restrict__ feat, const float* __restrict__ W,
    float* __restrict__ h, int n)
{
    __shared__ float Ws[N_IN * N_OUT];  // 16 KB
    for (int i = threadIdx.x; i < (N_IN * N_OUT) / 4; i += 256)
        reinterpret_cast<float4*>(Ws)[i] = reinterpret_cast<const float4*>(W)[i];
    __syncthreads();

    int gid = blockIdx.x * 256 + threadIdx.x;
    int row = gid >> 3;
    if (row >= n) return;
    int cg = (gid & 7) * 4;  // column group start

    const float4* frow = reinterpret_cast<const float4*>(feat + (size_t)row * N_IN);
    float4 acc = make_float4(0.f, 0.f, 0.f, 0.f);
    #pragma unroll
    for (int k4 = 0; k4 < N_IN / 4; ++k4) {
        float4 f = frow[k4];
        int k = k4 * 4;
        float4 w0 = *reinterpret_cast<const float4*>(&Ws[(k + 0) * N_OUT + cg]);
        float4 w1 = *reinterpret_cast<const float4*>(&Ws[(k + 1) * N_OUT + cg]);
        float4 w2 = *reinterpret_cast<const float4*>(&Ws[(k + 2) * N_OUT + cg]);
        float4 w3 = *reinterpret_cast<const float4*>(&Ws[(k + 3) * N_OUT + cg]);
        acc.x += f.x * w0.x + f.y * w1.x + f.z * w2.x + f.w * w3.x;
        acc.y += f.x * w0.y + f.y * w1.y + f.z * w2.y + f.w * w3.y;
        acc.z += f.x * w0.z + f.y * w1.z + f.z * w2.z + f.w * w3.z;
        acc.w += f.x * w0.w + f.y * w1.w + f.z * w2.w + f.w * w3.w;
    }
    *reinterpret_cast<float4*>(h + (size_t)row * N_OUT + cg) = acc;
}

// ---------------- Kernel 2: scatter-add messages ----------------
// 8 threads per edge; each handles 4 features: out[dst] += h[src] * edge_w.
__global__ __launch_bounds__(256) void scatter_add(
    const float* __restrict__ h, const float* __restrict__ edge_w,
    const int* __restrict__ src, const int* __restrict__ dst,
    float* __restrict__ out, int E)
{
    int gid = blockIdx.x * 256 + threadIdx.x;
    int e = gid >> 3;
    if (e >= E) return;
    int cg = (gid & 7) * 4;

    int s = src[e];
    int d = dst[e];
    float w = edge_w[e];
    float4 hv = *reinterpret_cast<const float4*>(h + (size_t)s * N_OUT + cg);
    float* o = out + (size_t)d * N_OUT + cg;
    atomicAdd(o + 0, hv.x * w);
    atomicAdd(o + 1, hv.y * w);
    atomicAdd(o + 2, hv.z * w);
    atomicAdd(o + 3, hv.w * w);
}

// ---------------- Fallback: fused (no workspace) ----------------
__global__ __launch_bounds__(256) void fused_edge(
    const float* __restrict__ feat, const float* __restrict__ W,
    const float* __restrict__ edge_w, const int* __restrict__ src,
    const int* __restrict__ dst, float* __restrict__ out, int E)
{
    __shared__ float Ws[N_IN * N_OUT];
    for (int i = threadIdx.x; i < (N_IN * N_OUT) / 4; i += 256)
        reinterpret_cast<float4*>(Ws)[i] = reinterpret_cast<const float4*>(W)[i];
    __syncthreads();

    int gid = blockIdx.x * 256 + threadIdx.x;
    int e = gid >> 3;
    if (e >= E) return;
    int cg = (gid & 7) * 4;

    int s = src[e];
    int d = dst[e];
    float w = edge_w[e];
    const float4* frow = reinterpret_cast<const float4*>(feat + (size_t)s * N_IN);
    float4 acc = make_float4(0.f, 0.f, 0.f, 0.f);
    #pragma unroll
    for (int k4 = 0; k4 < N_IN / 4; ++k4) {
        float4 f = frow[k4];
        int k = k4 * 4;
        float4 w0 = *reinterpret_cast<const float4*>(&Ws[(k + 0) * N_OUT + cg]);
        float4 w1 = *reinterpret_cast<const float4*>(&Ws[(k + 1) * N_OUT + cg]);
        float4 w2 = *reinterpret_cast<const float4*>(&Ws[(k + 2) * N_OUT + cg]);
        float4 w3 = *reinterpret_cast<const float4*>(&Ws[(k + 3) * N_OUT + cg]);
        acc.x += f.x * w0.x + f.y * w1.x + f.z * w2.x + f.w * w3.x;
        acc.y += f.x * w0.y + f.y * w1.y + f.z * w2.y + f.w * w3.y;
        acc.z += f.x * w0.z + f.y * w1.z + f.z * w2.z + f.w * w3.z;
        acc.w += f.x * w0.w + f.y * w1.w + f.z * w2.w + f.w * w3.w;
    }
    float* o = out + (size_t)d * N_OUT + cg;
    atomicAdd(o + 0, acc.x * w);
    atomicAdd(o + 1, acc.y * w);
    atomicAdd(o + 2, acc.z * w);
    atomicAdd(o + 3, acc.w * w);
}

extern "C" void kernel_launch(void* const* d_in, const int* in_sizes, int n_in,
                              void* d_out, int out_size, void* d_ws, size_t ws_size,
                              hipStream_t stream) {
    const float* feat   = (const float*)d_in[0];
    const float* W      = (const float*)d_in[1];
    const float* edge_w = (const float*)d_in[2];
    const int*   src    = (const int*)d_in[3];
    const int*   dst    = (const int*)d_in[4];
    float* out = (float*)d_out;

    int n = in_sizes[0] / N_IN;   // 100000
    int E = in_sizes[2];          // 1600000

    // zero the output accumulator (harness poisons it with 0xAA)
    hipMemsetAsync(d_out, 0, (size_t)out_size * sizeof(float), stream);

    size_t h_bytes = (size_t)n * N_OUT * sizeof(float);
    if (ws_size >= h_bytes) {
        float* h = (float*)d_ws;
        long gthreads = (long)n * 8;
        gemm_h<<<(int)((gthreads + 255) / 256), 256, 0, stream>>>(feat, W, h, n);
        long sthreads = (long)E * 8;
        scatter_add<<<(int)((sthreads + 255) / 256), 256, 0, stream>>>(h, edge_w, src, dst, out, E);
    } else {
        long sthreads = (long)E * 8;
        fused_edge<<<(int)((sthreads + 255) / 256), 256, 0, stream>>>(feat, W, edge_w, src, dst, out, E);
    }
}